// Round 13
// baseline (1524.662 us; speedup 1.0000x reference)
//
#include <hip/hip_runtime.h>
#include <hip/hip_bf16.h>
#include <hip/hip_fp16.h>
#include <math.h>

// x:(2048,3,32,32) f32; idx; w1:(128,3,4,4); b1:(128); w2:(256,128,4,4); b2:(256)
// cb0/cb1/cb2:(512,256); fc1_w:(512,16384); fc1_b:(512); fc2_w:(10,512); fc2_b:(10)
// out: 2048*10 logits ++ loss ++ perplexity = 20482 f32
// Precision: conv1 fp32; conv2 split-f16 MFMA (hi + lo*2^-11); VQ bf16 MFMA screen
// + exact f64 rescore of 16 cands; fc1 bf16 MFMA; fc2 fp32.
// R21 post-mortem: 2-img B-share ~flat (60->~57; total 1491->1489). Stall is B-load
// LATENCY in the use->load chain, not traffic. R12's explicit pipeline failed at
// 128-VGPR cap (collapsed); R21 kernel is 512thr/1-block = 256 VGPR available.
// R22: 4-deep named B register sets (B0..B3 = 64 VGPR), fully unrolled 16-tap
// schedule DOTAP(t,set)+LOADB(t+4,set) -> each set has ~360cy of MFMA to land.
// Same MFMA order -> bit-exact fea. fc1g/vqg stride-40 retained (verified).

#define CHUNK 256
#define NCH 8

typedef __attribute__((ext_vector_type(8))) short short8;            // 8 bf16
typedef __attribute__((ext_vector_type(8))) _Float16 half8;          // 8 f16
typedef __attribute__((ext_vector_type(8))) unsigned short ushort8v;
typedef __attribute__((ext_vector_type(4))) float f32x4;

__device__ inline unsigned short f2bf(float v) {
    __hip_bfloat16 h = __float2bfloat16(v);   // RNE
    return *reinterpret_cast<unsigned short*>(&h);
}

// LDS byte-address swizzle: XOR bank bits 4..6 with higher bits {7, 9^13, 12}.
// Bijective involution; keeps 16B alignment. Bit 14 (img select) untouched.
__device__ inline int swz(int a) {
    return a ^ ((a >> 3) & 16) ^ ((((a >> 9) ^ (a >> 13)) & 1) << 5) ^ ((a >> 6) & 64);
}

// ---------------- conv1: fp32; grid (CHUNK,4): block = (image, 4-of-16 cg) ----------------
// Emits split-f16 h, slab layout [b][cg][px][8ci] (lane-contiguous 16B stores).
__global__ __launch_bounds__(256) void k_conv1(const float* __restrict__ x,
                                               const float* __restrict__ w1,
                                               const float* __restrict__ b1,
                                               unsigned short* __restrict__ h_hi,
                                               unsigned short* __restrict__ h_lo) {
    __shared__ float xs[3 * 32 * 32];
    int b = blockIdx.x, yg = blockIdx.y, t = threadIdx.x;
    const float* xb = x + (size_t)b * 3072;
    for (int i = t; i < 768; i += 256)
        ((float4*)xs)[i] = ((const float4*)xb)[i];
    __syncthreads();
    int py = t >> 4, px = t & 15;
    float win[48];
#pragma unroll
    for (int ci = 0; ci < 3; ci++)
#pragma unroll
        for (int ky = 0; ky < 4; ky++) {
            int iy = 2 * py - 1 + ky;
#pragma unroll
            for (int kx = 0; kx < 4; kx++) {
                int ix = 2 * px - 1 + kx;
                bool ok = ((unsigned)iy < 32u) && ((unsigned)ix < 32u);
                win[ci * 16 + ky * 4 + kx] = ok ? xs[ci * 1024 + iy * 32 + ix] : 0.f;
            }
        }
#pragma unroll 1
    for (int cg = yg * 4; cg < yg * 4 + 4; cg++) {
        ushort8v hi8, lo8;
#pragma unroll
        for (int j = 0; j < 8; j++) {
            int co = cg * 8 + j;
            const float* w = w1 + co * 48;    // wave-uniform -> scalar K$ loads
            float acc = b1[co];
#pragma unroll
            for (int q = 0; q < 48; q++) acc = fmaf(win[q], w[q], acc);
            float v = fmaxf(acc, 0.f);
            __half hh = __float2half(v);
            float hf = __half2float(hh);
            __half ll = __float2half((v - hf) * 2048.0f);   // lo scaled 2^11: normal range
            hi8[j] = __half_as_ushort(hh);
            lo8[j] = __half_as_ushort(ll);
        }
        size_t go = (((size_t)b * 16 + cg) * 256 + t) * 8;
        *(ushort8v*)(h_hi + go) = hi8;
        *(ushort8v*)(h_lo + go) = lo8;
    }
}

// ---------------- w2 prep: [co][ci][tap] -> split-f16 MFMA fragment order ----------------
// Layout: [nh][tap][c4][jb][lane][8]; lane L (quad=L>>4, lc=L&15) holds
// W(co = nh*128 + jb*16 + lc, ci = c4*32 + quad*8 + h, tap).
__global__ __launch_bounds__(256) void k_w2p(const float* __restrict__ w2,
                                             unsigned short* __restrict__ WBh,
                                             unsigned short* __restrict__ WBl) {
    int gid = blockIdx.x * 256 + threadIdx.x;          // 0..65535
    int L = gid & 63;
    int jb = (gid >> 6) & 7;
    int c4 = (gid >> 9) & 3;
    int tap = (gid >> 11) & 15;
    int nh = gid >> 15;
    int lc = L & 15, quad = L >> 4;
    int co = nh * 128 + jb * 16 + lc;
    ushort8v hi8, lo8;
#pragma unroll
    for (int h = 0; h < 8; h++) {
        int ci = c4 * 32 + quad * 8 + h;
        float v = w2[(size_t)co * 2048 + ci * 16 + tap];
        __half hh = __float2half(v);
        __half ll = __float2half((v - __half2float(hh)) * 2048.0f);
        hi8[h] = __half_as_ushort(hh);
        lo8[h] = __half_as_ushort(ll);
    }
    *(ushort8v*)(WBh + (size_t)gid * 8) = hi8;
    *(ushort8v*)(WBl + (size_t)gid * 8) = lo8;
}

// ---------------- conv2: 2-img blocks, 4-deep B register pipeline ----------------
// grid (imgp, nh), 512 thr = 8 waves. Wave w: px-half ph=w>>2, co-quarter cq=w&3;
// computes 2 imgs x 32 px x 32 co. Per c4 phase: stage 2 imgs' A slabs (64KB LDS,
// swizzled), then 16 taps fully unrolled with 4-deep B prefetch sets.
#define LOADB(tp, BH, BL)                                                    \
    {                                                                        \
        const unsigned short* wb_  = WBhb + (size_t)((tp) * 4 + c4) * 4096;  \
        const unsigned short* wlb_ = WBlb + (size_t)((tp) * 4 + c4) * 4096;  \
        BH[0] = *(const half8*)(wb_);                                        \
        BH[1] = *(const half8*)(wb_ + 512);                                  \
        BL[0] = *(const half8*)(wlb_);                                       \
        BL[1] = *(const half8*)(wlb_ + 512);                                 \
    }

#define DOTAP(tp, BH, BL)                                                    \
    {                                                                        \
        int ky_ = (tp) >> 2, kx_ = (tp) & 3;                                 \
        int iy0_ = 2 * ay0 - 1 + ky_, ix0_ = 2 * ax0 - 1 + kx_;              \
        int iy1_ = 2 * ay1 - 1 + ky_, ix1_ = 2 * ax1 - 1 + kx_;              \
        bool v0_ = ((unsigned)iy0_ < 16u) && ((unsigned)ix0_ < 16u);         \
        bool v1_ = ((unsigned)iy1_ < 16u) && ((unsigned)ix1_ < 16u);         \
        int pin0_ = v0_ ? (iy0_ * 16 + ix0_) : 0;                            \
        int pin1_ = v1_ ? (iy1_ * 16 + ix1_) : 0;                            \
        int o0_ = swz((quad * 256 + pin0_) * 16);                            \
        int o1_ = swz((quad * 256 + pin1_) * 16);                            \
        half8 ah_[2][2], al2_[2][2];                                         \
        _Pragma("unroll")                                                    \
        for (int im_ = 0; im_ < 2; im_++) {                                  \
            ah_[im_][0]  = *(const half8*)(As_hi + im_ * 16384 + o0_);       \
            al2_[im_][0] = *(const half8*)(As_lo + im_ * 16384 + o0_);       \
            ah_[im_][1]  = *(const half8*)(As_hi + im_ * 16384 + o1_);       \
            al2_[im_][1] = *(const half8*)(As_lo + im_ * 16384 + o1_);       \
            ah_[im_][0]  = v0_ ? ah_[im_][0]  : zero8;                       \
            al2_[im_][0] = v0_ ? al2_[im_][0] : zero8;                       \
            ah_[im_][1]  = v1_ ? ah_[im_][1]  : zero8;                       \
            al2_[im_][1] = v1_ ? al2_[im_][1] : zero8;                       \
        }                                                                    \
        _Pragma("unroll")                                                    \
        for (int im_ = 0; im_ < 2; im_++)                                    \
            _Pragma("unroll")                                                \
            for (int i_ = 0; i_ < 2; i_++)                                   \
                _Pragma("unroll")                                            \
                for (int j_ = 0; j_ < 2; j_++) {                             \
                    a0[im_][i_][j_] = __builtin_amdgcn_mfma_f32_16x16x32_f16(ah_[im_][i_],  BH[j_], a0[im_][i_][j_], 0, 0, 0); \
                    a1[im_][i_][j_] = __builtin_amdgcn_mfma_f32_16x16x32_f16(ah_[im_][i_],  BL[j_], a1[im_][i_][j_], 0, 0, 0); \
                    a1[im_][i_][j_] = __builtin_amdgcn_mfma_f32_16x16x32_f16(al2_[im_][i_], BH[j_], a1[im_][i_][j_], 0, 0, 0); \
                }                                                            \
    }

__global__ __launch_bounds__(512, 1) void k_conv2m(const unsigned short* __restrict__ h_hi,
                                                   const unsigned short* __restrict__ h_lo,
                                                   const unsigned short* __restrict__ WBh,
                                                   const unsigned short* __restrict__ WBl,
                                                   const float* __restrict__ b2,
                                                   float* __restrict__ fea,
                                                   unsigned short* __restrict__ fea_bf) {
    __shared__ __align__(16) char As_hi[32768];
    __shared__ __align__(16) char As_lo[32768];
    int imgp = blockIdx.x, nh = blockIdx.y, t = threadIdx.x;
    int L = t & 63, w = t >> 6;
    int quad = L >> 4, lc = L & 15;
    int ph = w >> 2, cq = w & 3;
    int px0 = ph * 32 + lc, px1 = ph * 32 + 16 + lc;
    int ay0 = px0 >> 3, ax0 = px0 & 7;
    int ay1 = px1 >> 3, ax1 = px1 & 7;
    // B fragment base: [nh][tap][c4][jb][L][8]; this wave covers jb = cq*2 + j
    const unsigned short* WBhb = WBh + ((size_t)nh << 18) + (size_t)(cq * 1024 + L * 8);
    const unsigned short* WBlb = WBl + ((size_t)nh << 18) + (size_t)(cq * 1024 + L * 8);
    const half8 zero8 = {(_Float16)0, (_Float16)0, (_Float16)0, (_Float16)0,
                         (_Float16)0, (_Float16)0, (_Float16)0, (_Float16)0};
    const uint4* GH = (const uint4*)h_hi;
    const uint4* GL = (const uint4*)h_lo;
    size_t gbase = (size_t)imgp * 8192;           // uint4 units: img-pair base
    f32x4 a0[2][2][2], a1[2][2][2];               // [im][i(px-tile)][j]
#pragma unroll
    for (int im = 0; im < 2; im++)
#pragma unroll
        for (int i = 0; i < 2; i++)
#pragma unroll
            for (int j = 0; j < 2; j++) {
                a0[im][i][j] = (f32x4){0.f, 0.f, 0.f, 0.f};
                a1[im][i][j] = (f32x4){0.f, 0.f, 0.f, 0.f};
            }
#pragma unroll 1
    for (int c4 = 0; c4 < 4; c4++) {
        // ---- stage A slabs of both imgs for this c4: 2048 x 16B per buffer ----
        __syncthreads();                       // prior phase's reads done
#pragma unroll
        for (int u = 0; u < 4; u++) {
            int i = u * 512 + t;               // slot: im*1024 + p*256 + pin
            int im = i >> 10;
            size_t gidx = gbase + (size_t)(c4 * 1024 + im * 3072 + i);
            *(uint4*)(As_hi + swz(i * 16)) = GH[gidx];
            *(uint4*)(As_lo + swz(i * 16)) = GL[gidx];
        }
        __syncthreads();
        // ---- 16 taps, 4-deep B prefetch pipeline ----
        half8 B0h[2], B0l[2], B1h[2], B1l[2], B2h[2], B2l[2], B3h[2], B3l[2];
        LOADB(0, B0h, B0l);
        LOADB(1, B1h, B1l);
        LOADB(2, B2h, B2l);
        LOADB(3, B3h, B3l);
        DOTAP(0,  B0h, B0l);  LOADB(4,  B0h, B0l);
        DOTAP(1,  B1h, B1l);  LOADB(5,  B1h, B1l);
        DOTAP(2,  B2h, B2l);  LOADB(6,  B2h, B2l);
        DOTAP(3,  B3h, B3l);  LOADB(7,  B3h, B3l);
        DOTAP(4,  B0h, B0l);  LOADB(8,  B0h, B0l);
        DOTAP(5,  B1h, B1l);  LOADB(9,  B1h, B1l);
        DOTAP(6,  B2h, B2l);  LOADB(10, B2h, B2l);
        DOTAP(7,  B3h, B3l);  LOADB(11, B3h, B3l);
        DOTAP(8,  B0h, B0l);  LOADB(12, B0h, B0l);
        DOTAP(9,  B1h, B1l);  LOADB(13, B1h, B1l);
        DOTAP(10, B2h, B2l);  LOADB(14, B2h, B2l);
        DOTAP(11, B3h, B3l);  LOADB(15, B3h, B3l);
        DOTAP(12, B0h, B0l);
        DOTAP(13, B1h, B1l);
        DOTAP(14, B2h, B2l);
        DOTAP(15, B3h, B3l);
    }
    const float c1 = 4.8828125e-4f;           // 2^-11
    float bb[2];
#pragma unroll
    for (int j = 0; j < 2; j++) bb[j] = b2[nh * 128 + cq * 32 + j * 16 + lc];
#pragma unroll
    for (int im = 0; im < 2; im++)
#pragma unroll
        for (int i = 0; i < 2; i++)
#pragma unroll
            for (int j = 0; j < 2; j++)
#pragma unroll
                for (int reg = 0; reg < 4; reg++) {
                    int px = ph * 32 + i * 16 + quad * 4 + reg;
                    int co = nh * 128 + cq * 32 + j * 16 + lc;
                    float v = a0[im][i][j][reg] + c1 * a1[im][i][j][reg] + bb[j];
                    v = fmaxf(v, 0.f);
                    size_t gi = ((size_t)(imgp * 2 + im) * 64 + px) * 256 + co;  // [img][px][co]
                    fea[gi] = v;
                    fea_bf[gi] = f2bf(v);
                }
}

// ---------------- combined codebook (f32 + bf16) ----------------
__global__ __launch_bounds__(256) void k_comb(const float* __restrict__ cb0,
                                              const float* __restrict__ cb1,
                                              const float* __restrict__ cb2,
                                              const int* __restrict__ idxp,
                                              float* __restrict__ C,
                                              unsigned short* __restrict__ Cbf) {
    int i = blockIdx.x * 256 + threadIdx.x;
    int idx = *idxp;
    const float4* lo = (const float4*)cb0;
    const float4* hi = (const float4*)((idx == 2) ? cb2 : ((idx == 1) ? cb1 : cb0));
    float4 v = (i < 32768) ? lo[i] : hi[i - 32768];
    ((float4*)C)[i] = v;
    ushort4 u = { f2bf(v.x), f2bf(v.y), f2bf(v.z), f2bf(v.w) };
    *(ushort4*)(Cbf + (size_t)i * 4) = u;
}

// ---------------- half code norms ----------------
__global__ __launch_bounds__(256) void k_cnorm(const float* __restrict__ C,
                                               const int* __restrict__ idxp,
                                               float* __restrict__ cnorm) {
    int c = blockIdx.x * 256 + threadIdx.x;
    int Kc = (*idxp == 0) ? 512 : 1024;
    if (c >= 1024) return;
    if (c >= Kc) { cnorm[c] = 3.0e38f; return; }
    const float* row = C + (size_t)c * 256;
    double s = 0.0;
    for (int d = 0; d < 256; d++) { double v = row[d]; s += v * v; }
    cnorm[c] = (float)(0.5 * s);
}

// ---------------- VQ screening: bf16 MFMA GEMM + fused top-2/128-codes ----------------
// As/Bs row stride 40 ushorts -> 2-way banks (free) on ds_read_b128.
__global__ __launch_bounds__(256) void k_vqg(const unsigned short* __restrict__ fea_bf,
                                             const unsigned short* __restrict__ Cbf,
                                             const float* __restrict__ cnorm,
                                             int* __restrict__ cand) {
    __shared__ char smem[20480];
    unsigned short* As = (unsigned short*)smem;                 // 128*40*2 = 10240 B
    unsigned short* Bs = (unsigned short*)(smem + 10240);       // 10240 B
    float* t2 = (float*)smem;                                    // 16384 B
    float* t3 = (float*)(smem + 16384);                          // 2048 B
    int t = threadIdx.x;
    int m0 = blockIdx.x * 128, n0 = blockIdx.y * 128;
    int L = t & 63, w = t >> 6;
    int quad = L >> 4, lc = L & 15;
    int mw = (w >> 1) * 64, nw = (w & 1) * 64;
    f32x4 acc[4][4];
#pragma unroll
    for (int i = 0; i < 4; i++)
#pragma unroll
        for (int j = 0; j < 4; j++) acc[i][j] = (f32x4){0.f, 0.f, 0.f, 0.f};
    for (int k0 = 0; k0 < 256; k0 += 32) {
        __syncthreads();
#pragma unroll
        for (int u = 0; u < 2; u++) {
            int idx = t + u * 256;
            int m = idx >> 2, kq = idx & 3;
            int gm = m0 + m;
            const unsigned short* ga = fea_bf + ((size_t)(gm >> 6) * 64 + (gm & 63)) * 256 + k0 + kq * 8;
            *(uint4*)(As + m * 40 + kq * 8) = *(const uint4*)ga;
            const unsigned short* gb = Cbf + (size_t)(n0 + m) * 256 + k0 + kq * 8;
            *(uint4*)(Bs + m * 40 + kq * 8) = *(const uint4*)gb;
        }
        __syncthreads();
        short8 a[4], bv[4];
#pragma unroll
        for (int i = 0; i < 4; i++)
            a[i] = *(const short8*)(As + (mw + i * 16 + lc) * 40 + quad * 8);
#pragma unroll
        for (int j = 0; j < 4; j++)
            bv[j] = *(const short8*)(Bs + (nw + j * 16 + lc) * 40 + quad * 8);
#pragma unroll
        for (int i = 0; i < 4; i++)
#pragma unroll
            for (int j = 0; j < 4; j++)
                acc[i][j] = __builtin_amdgcn_mfma_f32_16x16x32_bf16(a[i], bv[j], acc[i][j], 0, 0, 0);
    }
    float cn[4];
#pragma unroll
    for (int j = 0; j < 4; j++) cn[j] = cnorm[n0 + nw + j * 16 + lc];
    __syncthreads();
    for (int P = 0; P < 4; P++) {
        if ((w >> 1) == (P >> 1)) {
#pragma unroll
            for (int mi = 0; mi < 2; mi++) {
                int mt = (P & 1) * 2 + mi;
#pragma unroll
                for (int reg = 0; reg < 4; reg++) {
                    int rp = mi * 16 + quad * 4 + reg;
#pragma unroll
                    for (int j = 0; j < 4; j++)
                        t2[rp * 128 + nw + j * 16 + lc] = cn[j] - acc[mt][j][reg];
                }
            }
        }
        __syncthreads();
        if (t < 128) {
            int row = t >> 2, q = t & 3;
            const float* sr = &t2[row * 128 + q * 32];
            float v1 = 3.4e38f, v2 = 3.4e38f; int c1 = 0, c2 = 0;
            for (int e = 0; e < 32; e++) {
                float s = sr[e]; int c = q * 32 + e;
                if (s < v1) { v2 = v1; c2 = c1; v1 = s; c1 = c; }
                else if (s < v2) { v2 = s; c2 = c; }
            }
            float* e3 = &t3[(row * 4 + q) * 4];
            e3[0] = v1; e3[1] = __int_as_float(c1); e3[2] = v2; e3[3] = __int_as_float(c2);
        }
        __syncthreads();
        if (t < 32) {
            float v1 = 3.4e38f, v2 = 3.4e38f; int c1 = 0, c2 = 0;
            for (int q = 0; q < 4; q++) {
                const float* e3 = &t3[(t * 4 + q) * 4];
                float a1 = e3[0]; int a1c = __float_as_int(e3[1]);
                float a2 = e3[2]; int a2c = __float_as_int(e3[3]);
                if (a1 < v1) { v2 = v1; c2 = c1; v1 = a1; c1 = a1c; }
                else if (a1 < v2) { v2 = a1; c2 = a1c; }
                if (a2 < v1) { v2 = v1; c2 = c1; v1 = a2; c1 = a2c; }
                else if (a2 < v2) { v2 = a2; c2 = a2c; }
            }
            size_t row = (size_t)m0 + P * 32 + t;
            cand[row * 16 + blockIdx.y * 2 + 0] = n0 + c1;
            cand[row * 16 + blockIdx.y * 2 + 1] = n0 + c2;
        }
        __syncthreads();
    }
}

// ---------------- exact f64 rescore, 4-way ILP + float4 loads ----------------
__global__ __launch_bounds__(256) void k_rescore(const float* __restrict__ fea,
                                                 const float* __restrict__ C,
                                                 const int* __restrict__ cand,
                                                 int* __restrict__ enc,
                                                 double* __restrict__ dloss) {
    __shared__ double dsm[256];
    __shared__ int dim_[256];
    __shared__ double bsum[16];
    int t = threadIdx.x;
    int rr = blockIdx.x * 16 + (t >> 4);
    int j = t & 15;
    int c = cand[(size_t)rr * 16 + j];
    const float* row = C + (size_t)c * 256;
    const float* xrow = fea + (size_t)rr * 256;    // rr = chunk-local (img*64+px)
    double s0 = 0.0, s1 = 0.0, s2 = 0.0, s3 = 0.0;
#pragma unroll 4
    for (int d = 0; d < 256; d += 4) {
        float4 xv = *(const float4*)(xrow + d);
        float4 cv = *(const float4*)(row + d);
        double d0 = (double)xv.x - (double)cv.x;
        double d1 = (double)xv.y - (double)cv.y;
        double d2 = (double)xv.z - (double)cv.z;
        double d3 = (double)xv.w - (double)cv.w;
        s0 = fma(d0, d0, s0);
        s1 = fma(d1, d1, s1);
        s2 = fma(d2, d2, s2);
        s3 = fma(d3, d3, s3);
    }
    double s = (s0 + s1) + (s2 + s3);
    dsm[t] = s;
    dim_[t] = c;
    __syncthreads();
    if (j == 0) {
        double best = dsm[t]; int bi = dim_[t];
        for (int q = 1; q < 16; q++) {
            double v = dsm[t + q]; int ci = dim_[t + q];
            if (v < best || (v == best && ci < bi)) { best = v; bi = ci; }
        }
        enc[rr] = bi;
        bsum[t >> 4] = best;
    }
    __syncthreads();
    if (t == 0) {
        double acc = 0.0;
        for (int q = 0; q < 16; q++) acc += bsum[q];
        atomicAdd(dloss, acc);
    }
}

// ---------------- histogram ----------------
__global__ __launch_bounds__(256) void k_hist(const int* __restrict__ enc,
                                              int* __restrict__ counts) {
    __shared__ int hc[1024];
    for (int i = threadIdx.x; i < 1024; i += 256) hc[i] = 0;
    __syncthreads();
    int base = blockIdx.x * 1024;
    for (int i = threadIdx.x; i < 1024; i += 256) atomicAdd(&hc[enc[base + i]], 1);
    __syncthreads();
    for (int i = threadIdx.x; i < 1024; i += 256)
        if (hc[i]) atomicAdd(&counts[i], hc[i]);
}

// ---------------- Wt_bf[n][p][d] = bf16(fc1_w[n][d*64+p]) ----------------
__global__ __launch_bounds__(256) void k_wt(const float* __restrict__ W,
                                            unsigned short* __restrict__ Wt) {
    __shared__ float tile[64][65];
    int n = blockIdx.x;
    int d0 = blockIdx.y * 64;
    int t = threadIdx.x;
    const float* src = W + (size_t)n * 16384 + (size_t)d0 * 64;
#pragma unroll
    for (int u = 0; u < 4; u++) {
        int i = t + u * 256;
        float4 v = ((const float4*)src)[i];
        int dd = i >> 4;
        int p = (i & 15) << 2;
        tile[dd][p] = v.x; tile[dd][p + 1] = v.y; tile[dd][p + 2] = v.z; tile[dd][p + 3] = v.w;
    }
    __syncthreads();
    unsigned short* dst = Wt + (size_t)n * 16384 + d0;
#pragma unroll
    for (int u = 0; u < 4; u++) {
        int i = t + u * 256;
        int p = i >> 4;
        int dd = (i & 15) << 2;
        ushort4 v = { f2bf(tile[dd][p]), f2bf(tile[dd + 1][p]),
                      f2bf(tile[dd + 2][p]), f2bf(tile[dd + 3][p]) };
        *(ushort4*)(dst + (size_t)p * 256 + dd) = v;
    }
}

// ---------------- fc1 bf16 MFMA GEMM with gathered A, split-K z=8 ----------------
// Padded stride 40 + double-buffered dseg staging (1 barrier/dseg).
__global__ __launch_bounds__(256) void k_fc1g(const int* __restrict__ enc,
                                              const unsigned short* __restrict__ Cbf,
                                              const unsigned short* __restrict__ Wt,
                                              float* __restrict__ part) {
    __shared__ unsigned short As[2][128 * 40];
    __shared__ unsigned short Bs[2][128 * 40];
    __shared__ int encs[128];
    int t = threadIdx.x;
    int m0 = blockIdx.x * 128, n0 = blockIdx.y * 128;
    int L = t & 63, w = t >> 6;
    int quad = L >> 4, lc = L & 15;
    int mw = (w >> 1) * 64, nw = (w & 1) * 64;
    f32x4 acc[4][4];
#pragma unroll
    for (int i = 0; i < 4; i++)
#pragma unroll
        for (int j = 0; j < 4; j++) acc[i][j] = (f32x4){0.f, 0.f, 0.f, 0.f};
    int p0 = blockIdx.z * 8;
    for (int p = p0; p < p0 + 8; p++) {
        __syncthreads();                       // all waves done with prior buffers
        if (t < 128) encs[t] = enc[(size_t)(m0 + t) * 64 + p];
        __syncthreads();
        for (int ds8 = 0; ds8 < 8; ds8++) {
            int dseg = ds8 * 32;
            int buf = ds8 & 1;
#pragma unroll
            for (int u = 0; u < 2; u++) {
                int idx = t + u * 256;
                int m = idx >> 2, kq = idx & 3;
                const unsigned short* ga = Cbf + (size_t)encs[m] * 256 + dseg + kq * 8;
                *(uint4*)(&As[buf][m * 40 + kq * 8]) = *(const uint4*)ga;
                const unsigned short* gb = Wt + (size_t)(n0 + m) * 16384 + p * 256 + dseg + kq * 8;
                *(uint4*)(&Bs[buf][m * 40 + kq * 8]) = *(const uint4*)gb;
            }
            __syncthreads();
            short8 a[4], bv[4];
#pragma unroll
            for (int i = 0; i < 4; i++)
                a[i] = *(const short8*)(&As[buf][(mw + i * 16 + lc) * 40 + quad * 8]);
#pragma unroll
            for (int j = 0; j < 4; j++)
                bv[j] = *(const short8*)(&Bs[buf][(nw + j * 16 + lc) * 40 + quad * 8]);
#pragma unroll
            for (int i = 0; i < 4; i++)
#pragma unroll
                for (int j = 0; j < 4; j++)
                    acc[i][j] = __builtin_amdgcn_mfma_f32_16x16x32_bf16(a[i], bv[j], acc[i][j], 0, 0, 0);
        }
    }
    float* P = part + (size_t)blockIdx.z * (2048 * 512);
#pragma unroll
    for (int i = 0; i < 4; i++)
#pragma unroll
        for (int j = 0; j < 4; j++)
#pragma unroll
            for (int reg = 0; reg < 4; reg++) {
                int row = m0 + mw + i * 16 + quad * 4 + reg;
                int col = n0 + nw + j * 16 + lc;
                P[(size_t)row * 512 + col] = acc[i][j][reg];
            }
}

__global__ __launch_bounds__(256) void k_fc1fin(const float* __restrict__ part,
                                                const float* __restrict__ bias,
                                                float* __restrict__ h1) {
    int i = blockIdx.x * 256 + threadIdx.x;
    float s = 0.f;
#pragma unroll
    for (int z = 0; z < 8; z++) s += part[i + (size_t)z * 1048576];
    s += bias[i & 511];
    h1[i] = 0.5f * s * (1.f + erff(s * 0.70710678118654752f));
}

// ---------------- fc2 ----------------
__global__ __launch_bounds__(256) void k_fc2(const float* __restrict__ h1,
                                             const float* __restrict__ w,
                                             const float* __restrict__ bias,
                                             float* __restrict__ out) {
    int gid = blockIdx.x * 256 + threadIdx.x;
    if (gid >= 20480) return;
    int b = gid / 10, k = gid % 10;
    const float* hr = h1 + (size_t)b * 512;
    const float* wr = w + (size_t)k * 512;
    float acc = bias[k];
#pragma unroll 8
    for (int j = 0; j < 512; j++) acc = fmaf(hr[j], wr[j], acc);
    out[gid] = acc;
}

// ---------------- loss + perplexity ----------------
__global__ __launch_bounds__(256) void k_final(const int* __restrict__ counts,
                                               const double* __restrict__ dloss,
                                               const int* __restrict__ idxp,
                                               float* __restrict__ out) {
    __shared__ float sb[256];
    int t = threadIdx.x;
    int Kc = (*idxp == 0) ? 512 : 1024;
    float local = 0.f;
    for (int c = t; c < Kc; c += 256) {
        float pr = (float)counts[c] * (1.0f / 131072.0f);
        local += pr * logf(pr + 1e-10f);
    }
    sb[t] = local;
    __syncthreads();
    for (int o = 128; o > 0; o >>= 1) {
        if (t < o) sb[t] += sb[t + o];
        __syncthreads();
    }
    if (t == 0) {
        out[20480] = (float)(dloss[0] * 1.25 / (131072.0 * 256.0));
        out[20481] = expf(-sb[0]);
    }
}

extern "C" void kernel_launch(void* const* d_in, const int* in_sizes, int n_in,
                              void* d_out, int out_size, void* d_ws, size_t ws_size,
                              hipStream_t stream) {
    const float* x    = (const float*)d_in[0];
    const int*   idxp = (const int*)d_in[1];
    const float* w1   = (const float*)d_in[2];
    const float* b1   = (const float*)d_in[3];
    const float* w2   = (const float*)d_in[4];
    const float* b2   = (const float*)d_in[5];
    const float* cb0  = (const float*)d_in[6];
    const float* cb1  = (const float*)d_in[7];
    const float* cb2  = (const float*)d_in[8];
    const float* fc1w = (const float*)d_in[9];
    const float* fc1b = (const float*)d_in[10];
    const float* fc2w = (const float*)d_in[11];
    const float* fc2b = (const float*)d_in[12];
    float* out = (float*)d_out;

    char* ws = (char*)d_ws;
    size_t off = 0;
    unsigned short* h_hi   = (unsigned short*)(ws + off); off += (size_t)CHUNK * 256 * 128 * 2; // 16.78 MB
    unsigned short* h_lo   = (unsigned short*)(ws + off); off += (size_t)CHUNK * 256 * 128 * 2; // 16.78 MB
    float*          fea_c  = (float*)(ws + off);          off += (size_t)CHUNK * 16384 * 4;     // 16.78 MB
    unsigned short* fea_bf = (unsigned short*)(ws + off); off += (size_t)CHUNK * 16384 * 2;     //  8.39 MB
    unsigned short* Wt_bf  = (unsigned short*)(ws + off); off += (size_t)512 * 16384 * 2;       // 16.78 MB
    unsigned short* Wc_hi  = (unsigned short*)(ws + off); off += (size_t)256 * 2048 * 2;        //  1.05 MB
    unsigned short* Wc_lo  = (unsigned short*)(ws + off); off += (size_t)256 * 2048 * 2;        //  1.05 MB
    float*          Cc     = (float*)(ws + off);          off += (size_t)1024 * 256 * 4;        //  1.05 MB
    unsigned short* Cc_bf  = (unsigned short*)(ws + off); off += (size_t)1024 * 256 * 2;        //  0.52 MB
    float*          h1     = (float*)(ws + off);          off += (size_t)2048 * 512 * 4;        //  4.19 MB
    int*            cand   = (int*)(ws + off);            off += (size_t)CHUNK * 64 * 16 * 4;   //  1.05 MB
    int*            enc    = (int*)(ws + off);            off += (size_t)131072 * 4;            //  0.52 MB
    float*          cnorm  = (float*)(ws + off);          off += 1024 * 4;
    int*            counts = (int*)(ws + off);            off += 1024 * 4;
    double*         dloss  = (double*)(ws + off);         off += 8;
    // total ~85 MB; part (33.55 MB) aliases h_hi+h_lo (dead after chunk loop)
    float* part = (float*)h_hi;

    hipMemsetAsync(counts, 0, 1024 * 4 + 8, stream);   // counts + dloss (contiguous)

    k_comb<<<256, 256, 0, stream>>>(cb0, cb1, cb2, idxp, Cc, Cc_bf);
    k_cnorm<<<4, 256, 0, stream>>>(Cc, idxp, cnorm);
    k_wt<<<dim3(512, 4), 256, 0, stream>>>(fc1w, Wt_bf);
    k_w2p<<<256, 256, 0, stream>>>(w2, Wc_hi, Wc_lo);

    for (int c = 0; c < NCH; c++) {
        k_conv1<<<dim3(CHUNK, 4), 256, 0, stream>>>(x + (size_t)c * CHUNK * 3072, w1, b1, h_hi, h_lo);
        k_conv2m<<<dim3(CHUNK / 2, 2), 512, 0, stream>>>(h_hi, h_lo, Wc_hi, Wc_lo, b2, fea_c, fea_bf);
        k_vqg<<<dim3(128, 8), 256, 0, stream>>>(fea_bf, Cc_bf, cnorm, cand);
        k_rescore<<<(CHUNK * 64) / 16, 256, 0, stream>>>(fea_c, Cc, cand,
                                                         enc + (size_t)c * CHUNK * 64, dloss);
    }

    k_hist<<<128, 256, 0, stream>>>(enc, counts);
    k_fc1g<<<dim3(16, 4, 8), 256, 0, stream>>>(enc, Cc_bf, Wt_bf, part);
    k_fc1fin<<<4096, 256, 0, stream>>>(part, fc1b, h1);
    k_fc2<<<80, 256, 0, stream>>>(h1, fc2w, fc2b, out);
    k_final<<<1, 256, 0, stream>>>(counts, dloss, idxp, out);
}

// Round 14
// 1488.333 us; speedup vs baseline: 1.0244x; 1.0244x over previous
//
#include <hip/hip_runtime.h>
#include <hip/hip_bf16.h>
#include <hip/hip_fp16.h>
#include <math.h>

// x:(2048,3,32,32) f32; idx; w1:(128,3,4,4); b1:(128); w2:(256,128,4,4); b2:(256)
// cb0/cb1/cb2:(512,256); fc1_w:(512,16384); fc1_b:(512); fc2_w:(10,512); fc2_b:(10)
// out: 2048*10 logits ++ loss ++ perplexity = 20482 f32
// Precision: conv1 fp32; conv2 split-f16 MFMA (hi + lo*2^-11); VQ bf16 MFMA screen
// + exact f64 rescore of 16 cands; fc1 bf16 MFMA; fc2 fp32.
// R22 post-mortem: REGRESSED 1489->1525 (conv2m 57->62). VGPR stayed 80 -> the
// 4-deep named-B pipeline was collapsed by the compiler AGAIN (3rd failure of
// source-level pipelining: R12, R16, R22). Full unroll added overhead for nothing.
// R23: pure revert to verified R21 (1489us): conv2m 2-img blocks, rolled tap loop,
// B register-shared across imgs; fc1g stride-40 dbuf; vqg stride-40.

#define CHUNK 256
#define NCH 8

typedef __attribute__((ext_vector_type(8))) short short8;            // 8 bf16
typedef __attribute__((ext_vector_type(8))) _Float16 half8;          // 8 f16
typedef __attribute__((ext_vector_type(8))) unsigned short ushort8v;
typedef __attribute__((ext_vector_type(4))) float f32x4;

__device__ inline unsigned short f2bf(float v) {
    __hip_bfloat16 h = __float2bfloat16(v);   // RNE
    return *reinterpret_cast<unsigned short*>(&h);
}

// LDS byte-address swizzle: XOR bank bits 4..6 with higher bits {7, 9^13, 12}.
// Bijective involution; keeps 16B alignment. Bit 14 (img select) untouched.
__device__ inline int swz(int a) {
    return a ^ ((a >> 3) & 16) ^ ((((a >> 9) ^ (a >> 13)) & 1) << 5) ^ ((a >> 6) & 64);
}

// ---------------- conv1: fp32; grid (CHUNK,4): block = (image, 4-of-16 cg) ----------------
// Emits split-f16 h, slab layout [b][cg][px][8ci] (lane-contiguous 16B stores).
__global__ __launch_bounds__(256) void k_conv1(const float* __restrict__ x,
                                               const float* __restrict__ w1,
                                               const float* __restrict__ b1,
                                               unsigned short* __restrict__ h_hi,
                                               unsigned short* __restrict__ h_lo) {
    __shared__ float xs[3 * 32 * 32];
    int b = blockIdx.x, yg = blockIdx.y, t = threadIdx.x;
    const float* xb = x + (size_t)b * 3072;
    for (int i = t; i < 768; i += 256)
        ((float4*)xs)[i] = ((const float4*)xb)[i];
    __syncthreads();
    int py = t >> 4, px = t & 15;
    float win[48];
#pragma unroll
    for (int ci = 0; ci < 3; ci++)
#pragma unroll
        for (int ky = 0; ky < 4; ky++) {
            int iy = 2 * py - 1 + ky;
#pragma unroll
            for (int kx = 0; kx < 4; kx++) {
                int ix = 2 * px - 1 + kx;
                bool ok = ((unsigned)iy < 32u) && ((unsigned)ix < 32u);
                win[ci * 16 + ky * 4 + kx] = ok ? xs[ci * 1024 + iy * 32 + ix] : 0.f;
            }
        }
#pragma unroll 1
    for (int cg = yg * 4; cg < yg * 4 + 4; cg++) {
        ushort8v hi8, lo8;
#pragma unroll
        for (int j = 0; j < 8; j++) {
            int co = cg * 8 + j;
            const float* w = w1 + co * 48;    // wave-uniform -> scalar K$ loads
            float acc = b1[co];
#pragma unroll
            for (int q = 0; q < 48; q++) acc = fmaf(win[q], w[q], acc);
            float v = fmaxf(acc, 0.f);
            __half hh = __float2half(v);
            float hf = __half2float(hh);
            __half ll = __float2half((v - hf) * 2048.0f);   // lo scaled 2^11: normal range
            hi8[j] = __half_as_ushort(hh);
            lo8[j] = __half_as_ushort(ll);
        }
        size_t go = (((size_t)b * 16 + cg) * 256 + t) * 8;
        *(ushort8v*)(h_hi + go) = hi8;
        *(ushort8v*)(h_lo + go) = lo8;
    }
}

// ---------------- w2 prep: [co][ci][tap] -> split-f16 MFMA fragment order ----------------
// Layout: [nh][tap][c4][jb][lane][8]; lane L (quad=L>>4, lc=L&15) holds
// W(co = nh*128 + jb*16 + lc, ci = c4*32 + quad*8 + h, tap).
__global__ __launch_bounds__(256) void k_w2p(const float* __restrict__ w2,
                                             unsigned short* __restrict__ WBh,
                                             unsigned short* __restrict__ WBl) {
    int gid = blockIdx.x * 256 + threadIdx.x;          // 0..65535
    int L = gid & 63;
    int jb = (gid >> 6) & 7;
    int c4 = (gid >> 9) & 3;
    int tap = (gid >> 11) & 15;
    int nh = gid >> 15;
    int lc = L & 15, quad = L >> 4;
    int co = nh * 128 + jb * 16 + lc;
    ushort8v hi8, lo8;
#pragma unroll
    for (int h = 0; h < 8; h++) {
        int ci = c4 * 32 + quad * 8 + h;
        float v = w2[(size_t)co * 2048 + ci * 16 + tap];
        __half hh = __float2half(v);
        __half ll = __float2half((v - __half2float(hh)) * 2048.0f);
        hi8[h] = __half_as_ushort(hh);
        lo8[h] = __half_as_ushort(ll);
    }
    *(ushort8v*)(WBh + (size_t)gid * 8) = hi8;
    *(ushort8v*)(WBl + (size_t)gid * 8) = lo8;
}

// ---------------- conv2: split-f16 MFMA GEMM, 2-img blocks, B register-shared ----------------
// grid (imgp, nh), 512 thr = 8 waves. Wave w: px-half ph=w>>2, co-quarter cq=w&3;
// computes 2 imgs x 32 px x 32 co. Per c4 phase: stage 2 imgs' A slabs (64KB LDS,
// swizzled), then 16 taps of {4 B loads + 8 A ds_reads + 24 MFMA}. 8 barriers.
__global__ __launch_bounds__(512, 1) void k_conv2m(const unsigned short* __restrict__ h_hi,
                                                   const unsigned short* __restrict__ h_lo,
                                                   const unsigned short* __restrict__ WBh,
                                                   const unsigned short* __restrict__ WBl,
                                                   const float* __restrict__ b2,
                                                   float* __restrict__ fea,
                                                   unsigned short* __restrict__ fea_bf) {
    __shared__ __align__(16) char As_hi[32768];
    __shared__ __align__(16) char As_lo[32768];
    int imgp = blockIdx.x, nh = blockIdx.y, t = threadIdx.x;
    int L = t & 63, w = t >> 6;
    int quad = L >> 4, lc = L & 15;
    int ph = w >> 2, cq = w & 3;
    int px0 = ph * 32 + lc, px1 = ph * 32 + 16 + lc;
    int ay0 = px0 >> 3, ax0 = px0 & 7;
    int ay1 = px1 >> 3, ax1 = px1 & 7;
    // B fragment base: [nh][tap][c4][jb][L][8]; this wave covers jb = cq*2 + j
    const unsigned short* WBhb = WBh + ((size_t)nh << 18) + (size_t)(cq * 1024 + L * 8);
    const unsigned short* WBlb = WBl + ((size_t)nh << 18) + (size_t)(cq * 1024 + L * 8);
    const half8 zero8 = {(_Float16)0, (_Float16)0, (_Float16)0, (_Float16)0,
                         (_Float16)0, (_Float16)0, (_Float16)0, (_Float16)0};
    const uint4* GH = (const uint4*)h_hi;
    const uint4* GL = (const uint4*)h_lo;
    size_t gbase = (size_t)imgp * 8192;           // uint4 units: img-pair base
    f32x4 a0[2][2][2], a1[2][2][2];               // [im][i(px-tile)][j]
#pragma unroll
    for (int im = 0; im < 2; im++)
#pragma unroll
        for (int i = 0; i < 2; i++)
#pragma unroll
            for (int j = 0; j < 2; j++) {
                a0[im][i][j] = (f32x4){0.f, 0.f, 0.f, 0.f};
                a1[im][i][j] = (f32x4){0.f, 0.f, 0.f, 0.f};
            }
#pragma unroll 1
    for (int c4 = 0; c4 < 4; c4++) {
        // ---- stage A slabs of both imgs for this c4: 2048 x 16B per buffer ----
        __syncthreads();                       // prior phase's reads done
#pragma unroll
        for (int u = 0; u < 4; u++) {
            int i = u * 512 + t;               // slot: im*1024 + p*256 + pin
            int im = i >> 10;
            size_t gidx = gbase + (size_t)(c4 * 1024 + im * 3072 + i);
            *(uint4*)(As_hi + swz(i * 16)) = GH[gidx];
            *(uint4*)(As_lo + swz(i * 16)) = GL[gidx];
        }
        __syncthreads();
        // ---- 16 taps over this c4 ----
#pragma unroll 2
        for (int tap = 0; tap < 16; tap++) {
            int ky = tap >> 2, kx = tap & 3;
            int iy0 = 2 * ay0 - 1 + ky, ix0 = 2 * ax0 - 1 + kx;
            int iy1 = 2 * ay1 - 1 + ky, ix1 = 2 * ax1 - 1 + kx;
            bool v0 = ((unsigned)iy0 < 16u) && ((unsigned)ix0 < 16u);
            bool v1 = ((unsigned)iy1 < 16u) && ((unsigned)ix1 < 16u);
            int pin0 = v0 ? (iy0 * 16 + ix0) : 0;
            int pin1 = v1 ? (iy1 * 16 + ix1) : 0;
            // B first (long-latency global, shared across both imgs)
            const unsigned short* wb  = WBhb + (size_t)(tap * 4 + c4) * 4096;
            const unsigned short* wlb = WBlb + (size_t)(tap * 4 + c4) * 4096;
            half8 bh[2], bl[2];
#pragma unroll
            for (int j = 0; j < 2; j++) {
                bh[j] = *(const half8*)(wb + j * 512);
                bl[j] = *(const half8*)(wlb + j * 512);
            }
            int o0 = swz((quad * 256 + pin0) * 16);
            int o1 = swz((quad * 256 + pin1) * 16);
            half8 ah[2][2], al_[2][2];         // [im][pt]
#pragma unroll
            for (int im = 0; im < 2; im++) {
                ah[im][0]  = *(const half8*)(As_hi + im * 16384 + o0);
                al_[im][0] = *(const half8*)(As_lo + im * 16384 + o0);
                ah[im][1]  = *(const half8*)(As_hi + im * 16384 + o1);
                al_[im][1] = *(const half8*)(As_lo + im * 16384 + o1);
                ah[im][0]  = v0 ? ah[im][0]  : zero8;
                al_[im][0] = v0 ? al_[im][0] : zero8;
                ah[im][1]  = v1 ? ah[im][1]  : zero8;
                al_[im][1] = v1 ? al_[im][1] : zero8;
            }
#pragma unroll
            for (int im = 0; im < 2; im++)
#pragma unroll
                for (int i = 0; i < 2; i++)
#pragma unroll
                    for (int j = 0; j < 2; j++) {
                        a0[im][i][j] = __builtin_amdgcn_mfma_f32_16x16x32_f16(ah[im][i],  bh[j], a0[im][i][j], 0, 0, 0);
                        a1[im][i][j] = __builtin_amdgcn_mfma_f32_16x16x32_f16(ah[im][i],  bl[j], a1[im][i][j], 0, 0, 0);
                        a1[im][i][j] = __builtin_amdgcn_mfma_f32_16x16x32_f16(al_[im][i], bh[j], a1[im][i][j], 0, 0, 0);
                    }
        }
    }
    const float c1 = 4.8828125e-4f;           // 2^-11
    float bb[2];
#pragma unroll
    for (int j = 0; j < 2; j++) bb[j] = b2[nh * 128 + cq * 32 + j * 16 + lc];
#pragma unroll
    for (int im = 0; im < 2; im++)
#pragma unroll
        for (int i = 0; i < 2; i++)
#pragma unroll
            for (int j = 0; j < 2; j++)
#pragma unroll
                for (int reg = 0; reg < 4; reg++) {
                    int px = ph * 32 + i * 16 + quad * 4 + reg;
                    int co = nh * 128 + cq * 32 + j * 16 + lc;
                    float v = a0[im][i][j][reg] + c1 * a1[im][i][j][reg] + bb[j];
                    v = fmaxf(v, 0.f);
                    size_t gi = ((size_t)(imgp * 2 + im) * 64 + px) * 256 + co;  // [img][px][co]
                    fea[gi] = v;
                    fea_bf[gi] = f2bf(v);
                }
}

// ---------------- combined codebook (f32 + bf16) ----------------
__global__ __launch_bounds__(256) void k_comb(const float* __restrict__ cb0,
                                              const float* __restrict__ cb1,
                                              const float* __restrict__ cb2,
                                              const int* __restrict__ idxp,
                                              float* __restrict__ C,
                                              unsigned short* __restrict__ Cbf) {
    int i = blockIdx.x * 256 + threadIdx.x;
    int idx = *idxp;
    const float4* lo = (const float4*)cb0;
    const float4* hi = (const float4*)((idx == 2) ? cb2 : ((idx == 1) ? cb1 : cb0));
    float4 v = (i < 32768) ? lo[i] : hi[i - 32768];
    ((float4*)C)[i] = v;
    ushort4 u = { f2bf(v.x), f2bf(v.y), f2bf(v.z), f2bf(v.w) };
    *(ushort4*)(Cbf + (size_t)i * 4) = u;
}

// ---------------- half code norms ----------------
__global__ __launch_bounds__(256) void k_cnorm(const float* __restrict__ C,
                                               const int* __restrict__ idxp,
                                               float* __restrict__ cnorm) {
    int c = blockIdx.x * 256 + threadIdx.x;
    int Kc = (*idxp == 0) ? 512 : 1024;
    if (c >= 1024) return;
    if (c >= Kc) { cnorm[c] = 3.0e38f; return; }
    const float* row = C + (size_t)c * 256;
    double s = 0.0;
    for (int d = 0; d < 256; d++) { double v = row[d]; s += v * v; }
    cnorm[c] = (float)(0.5 * s);
}

// ---------------- VQ screening: bf16 MFMA GEMM + fused top-2/128-codes ----------------
// As/Bs row stride 40 ushorts -> 2-way banks (free) on ds_read_b128.
__global__ __launch_bounds__(256) void k_vqg(const unsigned short* __restrict__ fea_bf,
                                             const unsigned short* __restrict__ Cbf,
                                             const float* __restrict__ cnorm,
                                             int* __restrict__ cand) {
    __shared__ char smem[20480];
    unsigned short* As = (unsigned short*)smem;                 // 128*40*2 = 10240 B
    unsigned short* Bs = (unsigned short*)(smem + 10240);       // 10240 B
    float* t2 = (float*)smem;                                    // 16384 B
    float* t3 = (float*)(smem + 16384);                          // 2048 B
    int t = threadIdx.x;
    int m0 = blockIdx.x * 128, n0 = blockIdx.y * 128;
    int L = t & 63, w = t >> 6;
    int quad = L >> 4, lc = L & 15;
    int mw = (w >> 1) * 64, nw = (w & 1) * 64;
    f32x4 acc[4][4];
#pragma unroll
    for (int i = 0; i < 4; i++)
#pragma unroll
        for (int j = 0; j < 4; j++) acc[i][j] = (f32x4){0.f, 0.f, 0.f, 0.f};
    for (int k0 = 0; k0 < 256; k0 += 32) {
        __syncthreads();
#pragma unroll
        for (int u = 0; u < 2; u++) {
            int idx = t + u * 256;
            int m = idx >> 2, kq = idx & 3;
            int gm = m0 + m;
            const unsigned short* ga = fea_bf + ((size_t)(gm >> 6) * 64 + (gm & 63)) * 256 + k0 + kq * 8;
            *(uint4*)(As + m * 40 + kq * 8) = *(const uint4*)ga;
            const unsigned short* gb = Cbf + (size_t)(n0 + m) * 256 + k0 + kq * 8;
            *(uint4*)(Bs + m * 40 + kq * 8) = *(const uint4*)gb;
        }
        __syncthreads();
        short8 a[4], bv[4];
#pragma unroll
        for (int i = 0; i < 4; i++)
            a[i] = *(const short8*)(As + (mw + i * 16 + lc) * 40 + quad * 8);
#pragma unroll
        for (int j = 0; j < 4; j++)
            bv[j] = *(const short8*)(Bs + (nw + j * 16 + lc) * 40 + quad * 8);
#pragma unroll
        for (int i = 0; i < 4; i++)
#pragma unroll
            for (int j = 0; j < 4; j++)
                acc[i][j] = __builtin_amdgcn_mfma_f32_16x16x32_bf16(a[i], bv[j], acc[i][j], 0, 0, 0);
    }
    float cn[4];
#pragma unroll
    for (int j = 0; j < 4; j++) cn[j] = cnorm[n0 + nw + j * 16 + lc];
    __syncthreads();
    for (int P = 0; P < 4; P++) {
        if ((w >> 1) == (P >> 1)) {
#pragma unroll
            for (int mi = 0; mi < 2; mi++) {
                int mt = (P & 1) * 2 + mi;
#pragma unroll
                for (int reg = 0; reg < 4; reg++) {
                    int rp = mi * 16 + quad * 4 + reg;
#pragma unroll
                    for (int j = 0; j < 4; j++)
                        t2[rp * 128 + nw + j * 16 + lc] = cn[j] - acc[mt][j][reg];
                }
            }
        }
        __syncthreads();
        if (t < 128) {
            int row = t >> 2, q = t & 3;
            const float* sr = &t2[row * 128 + q * 32];
            float v1 = 3.4e38f, v2 = 3.4e38f; int c1 = 0, c2 = 0;
            for (int e = 0; e < 32; e++) {
                float s = sr[e]; int c = q * 32 + e;
                if (s < v1) { v2 = v1; c2 = c1; v1 = s; c1 = c; }
                else if (s < v2) { v2 = s; c2 = c; }
            }
            float* e3 = &t3[(row * 4 + q) * 4];
            e3[0] = v1; e3[1] = __int_as_float(c1); e3[2] = v2; e3[3] = __int_as_float(c2);
        }
        __syncthreads();
        if (t < 32) {
            float v1 = 3.4e38f, v2 = 3.4e38f; int c1 = 0, c2 = 0;
            for (int q = 0; q < 4; q++) {
                const float* e3 = &t3[(t * 4 + q) * 4];
                float a1 = e3[0]; int a1c = __float_as_int(e3[1]);
                float a2 = e3[2]; int a2c = __float_as_int(e3[3]);
                if (a1 < v1) { v2 = v1; c2 = c1; v1 = a1; c1 = a1c; }
                else if (a1 < v2) { v2 = a1; c2 = a1c; }
                if (a2 < v1) { v2 = v1; c2 = c1; v1 = a2; c1 = a2c; }
                else if (a2 < v2) { v2 = a2; c2 = a2c; }
            }
            size_t row = (size_t)m0 + P * 32 + t;
            cand[row * 16 + blockIdx.y * 2 + 0] = n0 + c1;
            cand[row * 16 + blockIdx.y * 2 + 1] = n0 + c2;
        }
        __syncthreads();
    }
}

// ---------------- exact f64 rescore, 4-way ILP + float4 loads ----------------
__global__ __launch_bounds__(256) void k_rescore(const float* __restrict__ fea,
                                                 const float* __restrict__ C,
                                                 const int* __restrict__ cand,
                                                 int* __restrict__ enc,
                                                 double* __restrict__ dloss) {
    __shared__ double dsm[256];
    __shared__ int dim_[256];
    __shared__ double bsum[16];
    int t = threadIdx.x;
    int rr = blockIdx.x * 16 + (t >> 4);
    int j = t & 15;
    int c = cand[(size_t)rr * 16 + j];
    const float* row = C + (size_t)c * 256;
    const float* xrow = fea + (size_t)rr * 256;    // rr = chunk-local (img*64+px)
    double s0 = 0.0, s1 = 0.0, s2 = 0.0, s3 = 0.0;
#pragma unroll 4
    for (int d = 0; d < 256; d += 4) {
        float4 xv = *(const float4*)(xrow + d);
        float4 cv = *(const float4*)(row + d);
        double d0 = (double)xv.x - (double)cv.x;
        double d1 = (double)xv.y - (double)cv.y;
        double d2 = (double)xv.z - (double)cv.z;
        double d3 = (double)xv.w - (double)cv.w;
        s0 = fma(d0, d0, s0);
        s1 = fma(d1, d1, s1);
        s2 = fma(d2, d2, s2);
        s3 = fma(d3, d3, s3);
    }
    double s = (s0 + s1) + (s2 + s3);
    dsm[t] = s;
    dim_[t] = c;
    __syncthreads();
    if (j == 0) {
        double best = dsm[t]; int bi = dim_[t];
        for (int q = 1; q < 16; q++) {
            double v = dsm[t + q]; int ci = dim_[t + q];
            if (v < best || (v == best && ci < bi)) { best = v; bi = ci; }
        }
        enc[rr] = bi;
        bsum[t >> 4] = best;
    }
    __syncthreads();
    if (t == 0) {
        double acc = 0.0;
        for (int q = 0; q < 16; q++) acc += bsum[q];
        atomicAdd(dloss, acc);
    }
}

// ---------------- histogram ----------------
__global__ __launch_bounds__(256) void k_hist(const int* __restrict__ enc,
                                              int* __restrict__ counts) {
    __shared__ int hc[1024];
    for (int i = threadIdx.x; i < 1024; i += 256) hc[i] = 0;
    __syncthreads();
    int base = blockIdx.x * 1024;
    for (int i = threadIdx.x; i < 1024; i += 256) atomicAdd(&hc[enc[base + i]], 1);
    __syncthreads();
    for (int i = threadIdx.x; i < 1024; i += 256)
        if (hc[i]) atomicAdd(&counts[i], hc[i]);
}

// ---------------- Wt_bf[n][p][d] = bf16(fc1_w[n][d*64+p]) ----------------
__global__ __launch_bounds__(256) void k_wt(const float* __restrict__ W,
                                            unsigned short* __restrict__ Wt) {
    __shared__ float tile[64][65];
    int n = blockIdx.x;
    int d0 = blockIdx.y * 64;
    int t = threadIdx.x;
    const float* src = W + (size_t)n * 16384 + (size_t)d0 * 64;
#pragma unroll
    for (int u = 0; u < 4; u++) {
        int i = t + u * 256;
        float4 v = ((const float4*)src)[i];
        int dd = i >> 4;
        int p = (i & 15) << 2;
        tile[dd][p] = v.x; tile[dd][p + 1] = v.y; tile[dd][p + 2] = v.z; tile[dd][p + 3] = v.w;
    }
    __syncthreads();
    unsigned short* dst = Wt + (size_t)n * 16384 + d0;
#pragma unroll
    for (int u = 0; u < 4; u++) {
        int i = t + u * 256;
        int p = i >> 4;
        int dd = (i & 15) << 2;
        ushort4 v = { f2bf(tile[dd][p]), f2bf(tile[dd + 1][p]),
                      f2bf(tile[dd + 2][p]), f2bf(tile[dd + 3][p]) };
        *(ushort4*)(dst + (size_t)p * 256 + dd) = v;
    }
}

// ---------------- fc1 bf16 MFMA GEMM with gathered A, split-K z=8 ----------------
// Padded stride 40 + double-buffered dseg staging (1 barrier/dseg).
__global__ __launch_bounds__(256) void k_fc1g(const int* __restrict__ enc,
                                              const unsigned short* __restrict__ Cbf,
                                              const unsigned short* __restrict__ Wt,
                                              float* __restrict__ part) {
    __shared__ unsigned short As[2][128 * 40];
    __shared__ unsigned short Bs[2][128 * 40];
    __shared__ int encs[128];
    int t = threadIdx.x;
    int m0 = blockIdx.x * 128, n0 = blockIdx.y * 128;
    int L = t & 63, w = t >> 6;
    int quad = L >> 4, lc = L & 15;
    int mw = (w >> 1) * 64, nw = (w & 1) * 64;
    f32x4 acc[4][4];
#pragma unroll
    for (int i = 0; i < 4; i++)
#pragma unroll
        for (int j = 0; j < 4; j++) acc[i][j] = (f32x4){0.f, 0.f, 0.f, 0.f};
    int p0 = blockIdx.z * 8;
    for (int p = p0; p < p0 + 8; p++) {
        __syncthreads();                       // all waves done with prior buffers
        if (t < 128) encs[t] = enc[(size_t)(m0 + t) * 64 + p];
        __syncthreads();
        for (int ds8 = 0; ds8 < 8; ds8++) {
            int dseg = ds8 * 32;
            int buf = ds8 & 1;
#pragma unroll
            for (int u = 0; u < 2; u++) {
                int idx = t + u * 256;
                int m = idx >> 2, kq = idx & 3;
                const unsigned short* ga = Cbf + (size_t)encs[m] * 256 + dseg + kq * 8;
                *(uint4*)(&As[buf][m * 40 + kq * 8]) = *(const uint4*)ga;
                const unsigned short* gb = Wt + (size_t)(n0 + m) * 16384 + p * 256 + dseg + kq * 8;
                *(uint4*)(&Bs[buf][m * 40 + kq * 8]) = *(const uint4*)gb;
            }
            __syncthreads();
            short8 a[4], bv[4];
#pragma unroll
            for (int i = 0; i < 4; i++)
                a[i] = *(const short8*)(&As[buf][(mw + i * 16 + lc) * 40 + quad * 8]);
#pragma unroll
            for (int j = 0; j < 4; j++)
                bv[j] = *(const short8*)(&Bs[buf][(nw + j * 16 + lc) * 40 + quad * 8]);
#pragma unroll
            for (int i = 0; i < 4; i++)
#pragma unroll
                for (int j = 0; j < 4; j++)
                    acc[i][j] = __builtin_amdgcn_mfma_f32_16x16x32_bf16(a[i], bv[j], acc[i][j], 0, 0, 0);
        }
    }
    float* P = part + (size_t)blockIdx.z * (2048 * 512);
#pragma unroll
    for (int i = 0; i < 4; i++)
#pragma unroll
        for (int j = 0; j < 4; j++)
#pragma unroll
            for (int reg = 0; reg < 4; reg++) {
                int row = m0 + mw + i * 16 + quad * 4 + reg;
                int col = n0 + nw + j * 16 + lc;
                P[(size_t)row * 512 + col] = acc[i][j][reg];
            }
}

__global__ __launch_bounds__(256) void k_fc1fin(const float* __restrict__ part,
                                                const float* __restrict__ bias,
                                                float* __restrict__ h1) {
    int i = blockIdx.x * 256 + threadIdx.x;
    float s = 0.f;
#pragma unroll
    for (int z = 0; z < 8; z++) s += part[i + (size_t)z * 1048576];
    s += bias[i & 511];
    h1[i] = 0.5f * s * (1.f + erff(s * 0.70710678118654752f));
}

// ---------------- fc2 ----------------
__global__ __launch_bounds__(256) void k_fc2(const float* __restrict__ h1,
                                             const float* __restrict__ w,
                                             const float* __restrict__ bias,
                                             float* __restrict__ out) {
    int gid = blockIdx.x * 256 + threadIdx.x;
    if (gid >= 20480) return;
    int b = gid / 10, k = gid % 10;
    const float* hr = h1 + (size_t)b * 512;
    const float* wr = w + (size_t)k * 512;
    float acc = bias[k];
#pragma unroll 8
    for (int j = 0; j < 512; j++) acc = fmaf(hr[j], wr[j], acc);
    out[gid] = acc;
}

// ---------------- loss + perplexity ----------------
__global__ __launch_bounds__(256) void k_final(const int* __restrict__ counts,
                                               const double* __restrict__ dloss,
                                               const int* __restrict__ idxp,
                                               float* __restrict__ out) {
    __shared__ float sb[256];
    int t = threadIdx.x;
    int Kc = (*idxp == 0) ? 512 : 1024;
    float local = 0.f;
    for (int c = t; c < Kc; c += 256) {
        float pr = (float)counts[c] * (1.0f / 131072.0f);
        local += pr * logf(pr + 1e-10f);
    }
    sb[t] = local;
    __syncthreads();
    for (int o = 128; o > 0; o >>= 1) {
        if (t < o) sb[t] += sb[t + o];
        __syncthreads();
    }
    if (t == 0) {
        out[20480] = (float)(dloss[0] * 1.25 / (131072.0 * 256.0));
        out[20481] = expf(-sb[0]);
    }
}

extern "C" void kernel_launch(void* const* d_in, const int* in_sizes, int n_in,
                              void* d_out, int out_size, void* d_ws, size_t ws_size,
                              hipStream_t stream) {
    const float* x    = (const float*)d_in[0];
    const int*   idxp = (const int*)d_in[1];
    const float* w1   = (const float*)d_in[2];
    const float* b1   = (const float*)d_in[3];
    const float* w2   = (const float*)d_in[4];
    const float* b2   = (const float*)d_in[5];
    const float* cb0  = (const float*)d_in[6];
    const float* cb1  = (const float*)d_in[7];
    const float* cb2  = (const float*)d_in[8];
    const float* fc1w = (const float*)d_in[9];
    const float* fc1b = (const float*)d_in[10];
    const float* fc2w = (const float*)d_in[11];
    const float* fc2b = (const float*)d_in[12];
    float* out = (float*)d_out;

    char* ws = (char*)d_ws;
    size_t off = 0;
    unsigned short* h_hi   = (unsigned short*)(ws + off); off += (size_t)CHUNK * 256 * 128 * 2; // 16.78 MB
    unsigned short* h_lo   = (unsigned short*)(ws + off); off += (size_t)CHUNK * 256 * 128 * 2; // 16.78 MB
    float*          fea_c  = (float*)(ws + off);          off += (size_t)CHUNK * 16384 * 4;     // 16.78 MB
    unsigned short* fea_bf = (unsigned short*)(ws + off); off += (size_t)CHUNK * 16384 * 2;     //  8.39 MB
    unsigned short* Wt_bf  = (unsigned short*)(ws + off); off += (size_t)512 * 16384 * 2;       // 16.78 MB
    unsigned short* Wc_hi  = (unsigned short*)(ws + off); off += (size_t)256 * 2048 * 2;        //  1.05 MB
    unsigned short* Wc_lo  = (unsigned short*)(ws + off); off += (size_t)256 * 2048 * 2;        //  1.05 MB
    float*          Cc     = (float*)(ws + off);          off += (size_t)1024 * 256 * 4;        //  1.05 MB
    unsigned short* Cc_bf  = (unsigned short*)(ws + off); off += (size_t)1024 * 256 * 2;        //  0.52 MB
    float*          h1     = (float*)(ws + off);          off += (size_t)2048 * 512 * 4;        //  4.19 MB
    int*            cand   = (int*)(ws + off);            off += (size_t)CHUNK * 64 * 16 * 4;   //  1.05 MB
    int*            enc    = (int*)(ws + off);            off += (size_t)131072 * 4;            //  0.52 MB
    float*          cnorm  = (float*)(ws + off);          off += 1024 * 4;
    int*            counts = (int*)(ws + off);            off += 1024 * 4;
    double*         dloss  = (double*)(ws + off);         off += 8;
    // total ~85 MB; part (33.55 MB) aliases h_hi+h_lo (dead after chunk loop)
    float* part = (float*)h_hi;

    hipMemsetAsync(counts, 0, 1024 * 4 + 8, stream);   // counts + dloss (contiguous)

    k_comb<<<256, 256, 0, stream>>>(cb0, cb1, cb2, idxp, Cc, Cc_bf);
    k_cnorm<<<4, 256, 0, stream>>>(Cc, idxp, cnorm);
    k_wt<<<dim3(512, 4), 256, 0, stream>>>(fc1w, Wt_bf);
    k_w2p<<<256, 256, 0, stream>>>(w2, Wc_hi, Wc_lo);

    for (int c = 0; c < NCH; c++) {
        k_conv1<<<dim3(CHUNK, 4), 256, 0, stream>>>(x + (size_t)c * CHUNK * 3072, w1, b1, h_hi, h_lo);
        k_conv2m<<<dim3(CHUNK / 2, 2), 512, 0, stream>>>(h_hi, h_lo, Wc_hi, Wc_lo, b2, fea_c, fea_bf);
        k_vqg<<<dim3(128, 8), 256, 0, stream>>>(fea_bf, Cc_bf, cnorm, cand);
        k_rescore<<<(CHUNK * 64) / 16, 256, 0, stream>>>(fea_c, Cc, cand,
                                                         enc + (size_t)c * CHUNK * 64, dloss);
    }

    k_hist<<<128, 256, 0, stream>>>(enc, counts);
    k_fc1g<<<dim3(16, 4, 8), 256, 0, stream>>>(enc, Cc_bf, Wt_bf, part);
    k_fc1fin<<<4096, 256, 0, stream>>>(part, fc1b, h1);
    k_fc2<<<80, 256, 0, stream>>>(h1, fc2w, fc2b, out);
    k_final<<<1, 256, 0, stream>>>(counts, dloss, idxp, out);
}